// Round 2
// baseline (286.007 us; speedup 1.0000x reference)
//
#include <hip/hip_runtime.h>

// PillarMaxPooling R14: kill device-scope atomics via bucket counting-sort.
// R13 post-mortem: fire-and-forget regressed (WRITE 85->101MB, dur 86->94us)
// -> kernel is atomic-line-RMW bound; the R12 read-filter was saving ~16% of
// dirty-line traffic. One-pass scatter floor ~85us. So: restructure.
//   pass1 hist:    800k atomicAdd over 3750 bucket counters (no return).
//   pass2 scatter: stream points sequentially (NT), materialize 36B records
//                  (x,y,z,m,f0..f4) at cursor slots -> pass-3 reads are
//                  SEQUENTIAL (R11 lesson: random GATHERS lose; these are
//                  region-local writes instead).
//   pass3 pool:    1 block per 32-pillar bucket; LDS atomicMax (ds_max, no
//                  coherence traffic); BN stats folded (as R12); output
//                  written ONCE, coalesced, non-atomic. No output memset.
//   finalize + transform unchanged.
// Fallback to proven R12 path (filtered scatter) if ws_size < ~29MB.
// Ledger: R7 scatter floor 74us(no stats); R12 85.8us (filter+stats);
// R13 94us (no filter); R11 gather-pool 122us. Harness constant ~85us.

#define CMLP 32
#define BN_EPS 1e-3f
#define PSIZE 0.075f
#define XMIN -54.0f
#define YMIN -54.0f
#define CZ   -1.0f   // 0.5*(Z_MIN+Z_MAX)
#define NREP 64      // stats replicas
#define SCATB 4096   // fallback scatter blocks
#define PPB 32       // pillars per bucket (LDS tile = 32*32*4B = 4KB)
#define HISTB 1024
#define SCAT2B 2048

// monotone float<->uint order map; u==0 unreachable from real data -> empty sentinel
__device__ __forceinline__ unsigned enc_f(float x) {
  unsigned b = __float_as_uint(x);
  return (b & 0x80000000u) ? ~b : (b | 0x80000000u);
}
__device__ __forceinline__ float dec_f(unsigned u) {
  unsigned b = (u & 0x80000000u) ? (u & 0x7fffffffu) : ~u;
  return __uint_as_float(b);
}

// ---------------- pass 1: bucket histogram ----------------
__global__ void __launch_bounds__(256) hist_kernel(
    const int* __restrict__ sidx, int* __restrict__ hist, int N) {
  const int stride = gridDim.x * 256;
  for (int p = blockIdx.x * 256 + threadIdx.x; p < N; p += stride) {
    int m = __builtin_nontemporal_load(&sidx[p]);
    atomicAdd(&hist[m >> 5], 1);  // PPB=32
  }
}

// ---------------- pass 1b: exclusive prefix + cursor init ----------------
__global__ void prefix_kernel(const int* __restrict__ hist,
                              int* __restrict__ offs, int* __restrict__ cur,
                              int nbkt) {
  __shared__ int part[257];
  const int t = threadIdx.x;
  const int chunk = (nbkt + 255) >> 8;
  const int lo = t * chunk;
  const int hi = (lo + chunk < nbkt) ? lo + chunk : nbkt;
  int s = 0;
  for (int i = lo; i < hi; i++) s += hist[i];
  part[t] = s;
  __syncthreads();
  if (t == 0) {
    int acc = 0;
    for (int i = 0; i < 256; i++) { int v = part[i]; part[i] = acc; acc += v; }
    part[256] = acc;
  }
  __syncthreads();
  int acc = part[t];
  for (int i = lo; i < hi; i++) {
    offs[i] = acc;
    cur[i] = acc;
    acc += hist[i];
  }
  if (t == 0) offs[nbkt] = part[256];
}

// ---------------- pass 2: materialize bucket-sorted records ----------------
__global__ void __launch_bounds__(256) bucket_scatter_kernel(
    const float* __restrict__ xyz, const float* __restrict__ ptf,
    const int* __restrict__ sidx, int* __restrict__ cur,
    float4* __restrict__ recA, float4* __restrict__ recB,
    float* __restrict__ recC, int N) {
  const int stride = gridDim.x * 256;
  for (int p = blockIdx.x * 256 + threadIdx.x; p < N; p += stride) {
    int m = __builtin_nontemporal_load(&sidx[p]);
    float x = __builtin_nontemporal_load(&xyz[3 * p]);
    float y = __builtin_nontemporal_load(&xyz[3 * p + 1]);
    float z = __builtin_nontemporal_load(&xyz[3 * p + 2]);
    float f0 = __builtin_nontemporal_load(&ptf[5 * p + 0]);
    float f1 = __builtin_nontemporal_load(&ptf[5 * p + 1]);
    float f2 = __builtin_nontemporal_load(&ptf[5 * p + 2]);
    float f3 = __builtin_nontemporal_load(&ptf[5 * p + 3]);
    float f4 = __builtin_nontemporal_load(&ptf[5 * p + 4]);
    int idx = atomicAdd(&cur[m >> 5], 1);
    recA[idx] = make_float4(x, y, z, __int_as_float(m));
    recB[idx] = make_float4(f0, f1, f2, f3);
    recC[idx] = f4;
  }
}

// ---------------- pass 3: per-bucket LDS max-pool + BN stats ----------------
__global__ void __launch_bounds__(256) pool_kernel(
    const float4* __restrict__ recA, const float4* __restrict__ recB,
    const float* __restrict__ recC, const int* __restrict__ offs,
    const float* __restrict__ W1, const float* __restrict__ gamma,
    const int* __restrict__ pil, float* __restrict__ stats_rep,
    unsigned* __restrict__ outenc, int M) {
  __shared__ unsigned lmax[PPB * CMLP];  // 4KB
  const int tid = threadIdx.x;
  const int c = tid & 31;
  for (int i = tid; i < PPB * CMLP; i += 256) lmax[i] = 0u;
  // folded weights (verified R13): h = x*wx + y*wy + z*wz + cx*nw0 + cy*nw1
  //                                  + c0 + ptf.w6..w10
  const float w0 = W1[0 * CMLP + c], w1 = W1[1 * CMLP + c];
  const float w2 = W1[2 * CMLP + c];
  const float wx = w0 + W1[3 * CMLP + c];
  const float wy = w1 + W1[4 * CMLP + c];
  const float wz = w2 + W1[5 * CMLP + c];
  const float nw0 = -w0, nw1 = -w1;
  const float c0 = -CZ * w2;
  const float w6 = W1[6 * CMLP + c], w7 = W1[7 * CMLP + c];
  const float w8 = W1[8 * CMLP + c], w9 = W1[9 * CMLP + c];
  const float w10 = W1[10 * CMLP + c];
  const float sgn = (gamma[c] < 0.f) ? -1.f : 1.f;
  const int b = blockIdx.x;
  const int base = offs[b], end = offs[b + 1];
  const int p0 = b * PPB;
  float s = 0.f, ss = 0.f;
  __syncthreads();
  // 8 half-waves; 32 lanes of a half-wave read the SAME record -> HW broadcast
  for (int i = base + (tid >> 5); i < end; i += 8) {
    float4 a = recA[i];
    float4 f = recB[i];
    float f4 = recC[i];
    int m = __float_as_int(a.w);
    float cx = fmaf((float)pil[3 * m + 2] + 0.5f, PSIZE, XMIN);
    float cy = fmaf((float)pil[3 * m + 1] + 0.5f, PSIZE, YMIN);
    float h = c0;
    h = fmaf(a.x, wx, h);
    h = fmaf(a.y, wy, h);
    h = fmaf(a.z, wz, h);
    h = fmaf(cx, nw0, h);
    h = fmaf(cy, nw1, h);
    h = fmaf(f.x, w6, h);
    h = fmaf(f.y, w7, h);
    h = fmaf(f.z, w8, h);
    h = fmaf(f.w, w9, h);
    h = fmaf(f4, w10, h);
    s += h;
    ss = fmaf(h, h, ss);
    atomicMax(&lmax[((m - p0) << 5) | c], enc_f(sgn * h));  // ds_max: cheap
  }
  __syncthreads();
  // coalesced one-shot output write (covers every element -> no memset)
  const int gbase = b * (PPB * CMLP);
  const int glim = M * CMLP;
#pragma unroll
  for (int k = 0; k < 4; k++) {
    int g = gbase + tid + k * 256;
    if (g < glim) outenc[g] = lmax[tid + k * 256];
  }
  // BN stats reduce (identical tail to R12)
  s += __shfl_xor(s, 32);
  ss += __shfl_xor(ss, 32);
  __shared__ float red[4][64];
  const int wave = tid >> 6, lane = tid & 63;
  if (lane < 32) {
    red[wave][lane] = s;
    red[wave][32 + lane] = ss;
  }
  __syncthreads();
  if (tid < 64) {
    float v = red[0][tid] + red[1][tid] + red[2][tid] + red[3][tid];
    atomicAdd(&stats_rep[(blockIdx.x & (NREP - 1)) * 64 + tid], v);
  }
}

// ---------------- fallback: proven R12 filtered scatter ----------------
__global__ void __launch_bounds__(256) scatter_stats_kernel(
    const float* __restrict__ xyz, const float* __restrict__ ptf,
    const float* __restrict__ W1, const float* __restrict__ gamma,
    const int* __restrict__ pil, const int* __restrict__ sidx,
    float* __restrict__ stats_rep, unsigned* __restrict__ outenc, int N) {
  const int tid = threadIdx.x;
  const int c = tid & 31;
  const float w0 = W1[0 * CMLP + c], w1 = W1[1 * CMLP + c];
  const float w2 = W1[2 * CMLP + c];
  const float wx = w0 + W1[3 * CMLP + c];
  const float wy = w1 + W1[4 * CMLP + c];
  const float wz = w2 + W1[5 * CMLP + c];
  const float nw0 = -w0, nw1 = -w1;
  const float c0 = -CZ * w2;
  const float w6 = W1[6 * CMLP + c], w7 = W1[7 * CMLP + c];
  const float w8 = W1[8 * CMLP + c], w9 = W1[9 * CMLP + c];
  const float w10 = W1[10 * CMLP + c];
  const float sgn = (gamma[c] < 0.f) ? -1.f : 1.f;
  float s = 0.f, ss = 0.f;
  const int hw0 = (blockIdx.x * 256 + tid) >> 5;
  const int nhw = (SCATB * 256) >> 5;
  int p = hw0;
  int m = (p < N) ? sidx[p] : 0;
  while (p < N) {
    const int pn = p + nhw;
    const int mn = (pn < N) ? sidx[pn] : 0;
    float cx = fmaf((float)pil[3 * m + 2] + 0.5f, PSIZE, XMIN);
    float cy = fmaf((float)pil[3 * m + 1] + 0.5f, PSIZE, YMIN);
    float x = xyz[3 * p], y = xyz[3 * p + 1], z = xyz[3 * p + 2];
    float h = c0;
    h = fmaf(x, wx, h);
    h = fmaf(y, wy, h);
    h = fmaf(z, wz, h);
    h = fmaf(cx, nw0, h);
    h = fmaf(cy, nw1, h);
    h = fmaf(ptf[5 * p + 0], w6, h);
    h = fmaf(ptf[5 * p + 1], w7, h);
    h = fmaf(ptf[5 * p + 2], w8, h);
    h = fmaf(ptf[5 * p + 3], w9, h);
    h = fmaf(ptf[5 * p + 4], w10, h);
    s += h;
    ss = fmaf(h, h, ss);
    unsigned u = enc_f(sgn * h);
    unsigned* addr = &outenc[m * CMLP + c];
    if (u > *addr) atomicMax(addr, u);  // read-filter: saves ~16% dirty lines
    p = pn;
    m = mn;
  }
  s += __shfl_xor(s, 32);
  ss += __shfl_xor(ss, 32);
  __shared__ float red[4][64];
  const int wave = tid >> 6, lane = tid & 63;
  if (lane < 32) {
    red[wave][lane] = s;
    red[wave][32 + lane] = ss;
  }
  __syncthreads();
  if (tid < 64) {
    float v = red[0][tid] + red[1][tid] + red[2][tid] + red[3][tid];
    atomicAdd(&stats_rep[(blockIdx.x & (NREP - 1)) * 64 + tid], v);
  }
}

__global__ void finalize_kernel(const float* __restrict__ gamma,
                                const float* __restrict__ beta,
                                const float* __restrict__ stats_rep,
                                float* __restrict__ affine, float invN) {
  int c = threadIdx.x;
  if (c < CMLP) {
    float s = 0.f, ss = 0.f;
    for (int r = 0; r < NREP; r++) {
      s += stats_rep[r * 64 + c];
      ss += stats_rep[r * 64 + 32 + c];
    }
    float mean = s * invN;
    float var = ss * invN - mean * mean;          // biased, like jnp.var
    float sc = gamma[c] * rsqrtf(var + BN_EPS);
    affine[c] = sc;                               // scale
    affine[CMLP + c] = beta[c] - mean * sc;       // bias
  }
}

__global__ void __launch_bounds__(256) transform_kernel(
    unsigned* __restrict__ io, const float* __restrict__ affine, int total) {
  int i = blockIdx.x * 256 + threadIdx.x;
  if (i < total) {
    unsigned u = io[i];
    int c = i & 31;
    float v = 0.f;  // u==0 <=> empty pillar -> 0
    if (u) v = fmaxf(fmaf(fabsf(affine[c]), dec_f(u), affine[CMLP + c]), 0.f);
    io[i] = __float_as_uint(v);
  }
}

extern "C" void kernel_launch(void* const* d_in, const int* in_sizes, int n_in,
                              void* d_out, int out_size, void* d_ws, size_t ws_size,
                              hipStream_t stream) {
  const float* xyz = (const float*)d_in[0];
  const float* ptf = (const float*)d_in[1];
  const float* W1 = (const float*)d_in[2];
  const float* gamma = (const float*)d_in[3];
  const float* beta = (const float*)d_in[4];
  const int* pil = (const int*)d_in[5];
  const int* sidx = (const int*)d_in[6];
  unsigned* out = (unsigned*)d_out;

  int N = in_sizes[0] / 3;
  int M = out_size / CMLP;
  int nbkt = (M + PPB - 1) / PPB;

  // workspace layout
  char* w = (char*)d_ws;
  float* stats_rep = (float*)w;                 size_t off = NREP * 64 * sizeof(float);
  float* affine = (float*)(w + off);            off += 64 * sizeof(float);
  int* hist = (int*)(w + off);                  off += (size_t)nbkt * sizeof(int);
  int* offs = (int*)(w + off);                  off += (size_t)(nbkt + 1) * sizeof(int);
  int* cur = (int*)(w + off);                   off += (size_t)nbkt * sizeof(int);
  off = (off + 15) & ~(size_t)15;
  float4* recA = (float4*)(w + off);            off += (size_t)N * sizeof(float4);
  float4* recB = (float4*)(w + off);            off += (size_t)N * sizeof(float4);
  float* recC = (float*)(w + off);              off += (size_t)N * sizeof(float);

  hipMemsetAsync(stats_rep, 0, NREP * 64 * sizeof(float), stream);

  if (ws_size >= off) {
    // ---- bucket pipeline ----
    hipMemsetAsync(hist, 0, (size_t)nbkt * sizeof(int), stream);
    hist_kernel<<<HISTB, 256, 0, stream>>>(sidx, hist, N);
    prefix_kernel<<<1, 256, 0, stream>>>(hist, offs, cur, nbkt);
    bucket_scatter_kernel<<<SCAT2B, 256, 0, stream>>>(xyz, ptf, sidx, cur,
                                                      recA, recB, recC, N);
    pool_kernel<<<nbkt, 256, 0, stream>>>(recA, recB, recC, offs, W1, gamma,
                                          pil, stats_rep, out, M);
  } else {
    // ---- fallback: R12 proven path ----
    hipMemsetAsync(out, 0, (size_t)out_size * sizeof(unsigned), stream);
    scatter_stats_kernel<<<SCATB, 256, 0, stream>>>(xyz, ptf, W1, gamma, pil,
                                                    sidx, stats_rep, out, N);
  }
  finalize_kernel<<<1, 64, 0, stream>>>(gamma, beta, stats_rep, affine,
                                        1.0f / (float)N);
  transform_kernel<<<(out_size + 255) / 256, 256, 0, stream>>>(out, affine,
                                                               out_size);
}

// Round 3
// 185.179 us; speedup vs baseline: 1.5445x; 1.5445x over previous
//
#include <hip/hip_runtime.h>

// PillarMaxPooling R15: fully software-pipelined R12 scatter.
// R14 post-mortem: bucket sort dead -- record scatter has the same random
// line ping-pong as the atomics (WRITE 96MB, 75us, VALU 0.5%). Reverted.
// R12 counters (occ 78%, VALU 33%, BW 25%, nothing saturated) => the scatter
// is LATENCY-bound: per-iteration dependent pil-gather + filter-read stall.
// Fix: prefetch ONE FULL ITERATION ahead {m, pil_y, pil_x, xyz, ptf,
// filter word outenc[m*32+c]} so the body is FMA chain + compare-vs-register
// + filtered fire-and-forget atomic. Stale filter word => redundant atomic,
// still correct. Keep filter (R13: saves ~16% dirty lines), keep NT streams
// (R13: FETCH 85->35MB), plain cached loads for pil/outenc.
// Ledger: R12 85.8us scatter / 172 total (best); R13 no-filter 94us; R14
// bucket 286 total; R11 gather-pool 122us; R7 ~74us floor w/o stats/filter.
// Harness constant ~85us. Named scalars only (arrays spill).

#define CMLP 32
#define BN_EPS 1e-3f
#define PSIZE 0.075f
#define XMIN -54.0f
#define YMIN -54.0f
#define CZ   -1.0f   // 0.5*(Z_MIN+Z_MAX)
#define NREP 64      // stats replicas (64 lines apart)
#define SCATB 4096

// monotone float<->uint order map; u==0 unreachable from real data -> empty sentinel
__device__ __forceinline__ unsigned enc_f(float x) {
  unsigned b = __float_as_uint(x);
  return (b & 0x80000000u) ? ~b : (b | 0x80000000u);
}
__device__ __forceinline__ float dec_f(unsigned u) {
  unsigned b = (u & 0x80000000u) ? (u & 0x7fffffffu) : ~u;
  return __uint_as_float(b);
}

__global__ void __launch_bounds__(256) scatter_stats_kernel(
    const float* __restrict__ xyz, const float* __restrict__ ptf,
    const float* __restrict__ W1, const float* __restrict__ gamma,
    const int* __restrict__ pil, const int* __restrict__ sidx,
    float* __restrict__ stats_rep, unsigned* __restrict__ outenc, int N) {
  const int tid = threadIdx.x;
  const int c = tid & 31;
  // folded weights: h = x*wx + y*wy + z*wz - cx*w0 - cy*w1 - CZ*w2 + ptf.w
  const float w0 = W1[0 * CMLP + c], w1 = W1[1 * CMLP + c];
  const float w2 = W1[2 * CMLP + c];
  const float wx = w0 + W1[3 * CMLP + c];
  const float wy = w1 + W1[4 * CMLP + c];
  const float wz = w2 + W1[5 * CMLP + c];
  const float nw0 = -w0, nw1 = -w1;
  const float c0 = -CZ * w2;
  const float w6 = W1[6 * CMLP + c], w7 = W1[7 * CMLP + c];
  const float w8 = W1[8 * CMLP + c], w9 = W1[9 * CMLP + c];
  const float w10 = W1[10 * CMLP + c];
  const float sgn = (gamma[c] < 0.f) ? -1.f : 1.f;  // sign(sc)=sign(gamma)
  float s = 0.f, ss = 0.f;  // per-channel h moments
  // half-wave per point; 32 lanes issue the same addresses -> HW broadcast
  const int hw0 = (blockIdx.x * 256 + tid) >> 5;
  const int nhw = (SCATB * 256) >> 5;

  // ---- pipeline stage: state for CURRENT point, loaded one iter ahead ----
  int p = hw0;
  int m = 0, py = 0, px = 0;
  float x = 0.f, y = 0.f, z = 0.f, f0 = 0.f, f1 = 0.f, f2 = 0.f, f3 = 0.f,
        f4 = 0.f;
  unsigned uf = 0xffffffffu;  // filter word (never-pass default)
  if (p < N) {
    m = __builtin_nontemporal_load(&sidx[p]);
    py = pil[3 * m + 1];
    px = pil[3 * m + 2];
    x = __builtin_nontemporal_load(&xyz[3 * p]);
    y = __builtin_nontemporal_load(&xyz[3 * p + 1]);
    z = __builtin_nontemporal_load(&xyz[3 * p + 2]);
    f0 = __builtin_nontemporal_load(&ptf[5 * p + 0]);
    f1 = __builtin_nontemporal_load(&ptf[5 * p + 1]);
    f2 = __builtin_nontemporal_load(&ptf[5 * p + 2]);
    f3 = __builtin_nontemporal_load(&ptf[5 * p + 3]);
    f4 = __builtin_nontemporal_load(&ptf[5 * p + 4]);
    uf = outenc[m * CMLP + c];  // cached; stale => redundant atomic only
  }
  while (p < N) {
    const int pn = p + nhw;
    // ---- prefetch next point: issued before the FMA chain consumes cur ----
    int mn = 0, pyn = 0, pxn = 0;
    float xn = 0.f, yn = 0.f, zn = 0.f, g0 = 0.f, g1 = 0.f, g2 = 0.f,
          g3 = 0.f, g4 = 0.f;
    unsigned ufn = 0xffffffffu;
    if (pn < N) {
      mn = __builtin_nontemporal_load(&sidx[pn]);
      pyn = pil[3 * mn + 1];
      pxn = pil[3 * mn + 2];
      xn = __builtin_nontemporal_load(&xyz[3 * pn]);
      yn = __builtin_nontemporal_load(&xyz[3 * pn + 1]);
      zn = __builtin_nontemporal_load(&xyz[3 * pn + 2]);
      g0 = __builtin_nontemporal_load(&ptf[5 * pn + 0]);
      g1 = __builtin_nontemporal_load(&ptf[5 * pn + 1]);
      g2 = __builtin_nontemporal_load(&ptf[5 * pn + 2]);
      g3 = __builtin_nontemporal_load(&ptf[5 * pn + 3]);
      g4 = __builtin_nontemporal_load(&ptf[5 * pn + 4]);
      ufn = outenc[mn * CMLP + c];
    }
    // ---- compute on fully-resident registers ----
    float cx = fmaf((float)px + 0.5f, PSIZE, XMIN);
    float cy = fmaf((float)py + 0.5f, PSIZE, YMIN);
    float h = c0;
    h = fmaf(x, wx, h);
    h = fmaf(y, wy, h);
    h = fmaf(z, wz, h);
    h = fmaf(cx, nw0, h);
    h = fmaf(cy, nw1, h);
    h = fmaf(f0, w6, h);
    h = fmaf(f1, w7, h);
    h = fmaf(f2, w8, h);
    h = fmaf(f3, w9, h);
    h = fmaf(f4, w10, h);
    s += h;
    ss = fmaf(h, h, ss);
    unsigned u = enc_f(sgn * h);
    if (u > uf) atomicMax(&outenc[m * CMLP + c], u);  // no dependent wait
    // ---- rotate pipeline ----
    p = pn; m = mn; py = pyn; px = pxn;
    x = xn; y = yn; z = zn;
    f0 = g0; f1 = g1; f2 = g2; f3 = g3; f4 = g4;
    uf = ufn;
  }
  // lanes L and L+32 hold the same channel -> combine, stage, block-reduce
  s += __shfl_xor(s, 32);
  ss += __shfl_xor(ss, 32);
  __shared__ float red[4][64];
  const int wave = tid >> 6, lane = tid & 63;
  if (lane < 32) {
    red[wave][lane] = s;
    red[wave][32 + lane] = ss;
  }
  __syncthreads();
  if (tid < 64) {
    float v = red[0][tid] + red[1][tid] + red[2][tid] + red[3][tid];
    // replica blockIdx&63: 64 blocks/address -> no hot-line serialization
    atomicAdd(&stats_rep[(blockIdx.x & (NREP - 1)) * 64 + tid], v);
  }
}

__global__ void finalize_kernel(const float* __restrict__ gamma,
                                const float* __restrict__ beta,
                                const float* __restrict__ stats_rep,
                                float* __restrict__ affine, float invN) {
  int c = threadIdx.x;
  if (c < CMLP) {
    float s = 0.f, ss = 0.f;
    for (int r = 0; r < NREP; r++) {
      s += stats_rep[r * 64 + c];
      ss += stats_rep[r * 64 + 32 + c];
    }
    float mean = s * invN;
    float var = ss * invN - mean * mean;          // biased, like jnp.var
    float sc = gamma[c] * rsqrtf(var + BN_EPS);
    affine[c] = sc;                               // scale
    affine[CMLP + c] = beta[c] - mean * sc;       // bias
  }
}

__global__ void __launch_bounds__(256) transform_kernel(
    unsigned* __restrict__ io, const float* __restrict__ affine, int total) {
  int i = blockIdx.x * 256 + threadIdx.x;
  if (i < total) {
    unsigned u = io[i];
    int c = i & 31;
    float v = 0.f;  // u==0 <=> empty pillar -> 0 (matches max then relu floor)
    if (u) v = fmaxf(fmaf(fabsf(affine[c]), dec_f(u), affine[CMLP + c]), 0.f);
    io[i] = __float_as_uint(v);
  }
}

extern "C" void kernel_launch(void* const* d_in, const int* in_sizes, int n_in,
                              void* d_out, int out_size, void* d_ws, size_t ws_size,
                              hipStream_t stream) {
  const float* xyz = (const float*)d_in[0];
  const float* ptf = (const float*)d_in[1];
  const float* W1 = (const float*)d_in[2];
  const float* gamma = (const float*)d_in[3];
  const float* beta = (const float*)d_in[4];
  const int* pil = (const int*)d_in[5];
  const int* sidx = (const int*)d_in[6];
  unsigned* out = (unsigned*)d_out;

  int N = in_sizes[0] / 3;

  // ws: [0, 16KB) stats replicas (64 x {s[32], ss[32]}); [16KB, +256B) affine
  float* stats_rep = (float*)d_ws;
  float* affine = (float*)((char*)d_ws + NREP * 64 * sizeof(float));

  hipMemsetAsync(stats_rep, 0, NREP * 64 * sizeof(float), stream);
  hipMemsetAsync(out, 0, (size_t)out_size * sizeof(unsigned), stream);

  scatter_stats_kernel<<<SCATB, 256, 0, stream>>>(xyz, ptf, W1, gamma, pil,
                                                  sidx, stats_rep, out, N);
  finalize_kernel<<<1, 64, 0, stream>>>(gamma, beta, stats_rep, affine,
                                        1.0f / (float)N);
  transform_kernel<<<(out_size + 255) / 256, 256, 0, stream>>>(out, affine,
                                                               out_size);
}